// Round 13
// baseline (847.683 us; speedup 1.0000x reference)
//
#include <hip/hip_runtime.h>
#include <hip/hip_fp16.h>

typedef _Float16 f16;
typedef _Float16 f16x2 __attribute__((ext_vector_type(2)));
typedef _Float16 f16x4 __attribute__((ext_vector_type(4)));
typedef _Float16 f16x8 __attribute__((ext_vector_type(8)));
typedef float    f32x4 __attribute__((ext_vector_type(4)));

// Problem constants: B=64, S=32, P=49, F=2048, E=512, H=512, V=32000
// M=3136 (B*P) padded to 3200 for 128-row tiles.

#define GLD16(g, l)                                                        \
  __builtin_amdgcn_global_load_lds(                                        \
      (const __attribute__((address_space(1))) void*)(g),                  \
      (__attribute__((address_space(3))) void*)(l), 16, 0, 0)

static __device__ __forceinline__ float fdot2f(f16x2 a, f16x2 b, float c) {
#if __has_builtin(__builtin_amdgcn_fdot2)
  return __builtin_amdgcn_fdot2(a, b, c, false);
#else
  return c + (float)a.x * (float)b.x + (float)a.y * (float)b.y;
#endif
}

// ---------------- fused converts + packs + embedding gather (ONE dispatch) ----------------
// WhhP pack (R1-proven): uint4 at [k2*512 + j] = 4 gates x f16-pair (W_hh[g*512+j][2k2..2k2+1])
// UaT2 pack: f16x2 at dword [j2*512 + k] = (U_a[k][2j2], U_a[k][2j2+1])
__global__ __launch_bounds__(256) void k_prep(
    const float* __restrict__ feat, const float* __restrict__ W_a,
    const float* __restrict__ W_ih, const float* __restrict__ fc_W,
    const float* __restrict__ W_hh, const float* __restrict__ U_a,
    const float* __restrict__ Wh, const float* __restrict__ Wc,
    const int* __restrict__ caps, const float* __restrict__ etab,
    f16* __restrict__ feat_h, f16* __restrict__ W_a_h,
    f16* __restrict__ W_ih_h, f16* __restrict__ fc_W_h,
    f16* __restrict__ WhhP, f16* __restrict__ UaT2,
    f16* __restrict__ Whc_h, f16* __restrict__ Aemb) {
  const long c0 = 1605632;              // feat      (6422528 f32 /4)
  const long c1 = c0 + 262144;          // W_a
  const long c2 = c1 + 1310720;         // W_ih
  const long c3 = c2 + 4096000;         // fc_W
  const long c4 = c3 + 262144;          // W_hh -> WhhP pack
  const long c5 = c4 + 65536;           // U_a  -> UaT2 pack
  const long c6 = c5 + 262144;          // Wh   -> Whc rows 0..511
  const long c7 = c6 + 262144;          // Wc   -> Whc rows 512..1023
  const long c8 = c7 + 262144;          // embed: 2048 rows x 128 f16x4 chunks
  long i = (long)blockIdx.x * 256 + threadIdx.x;
  const long stride = (long)gridDim.x * 256;
  for (; i < c8; i += stride) {
    if (i >= c3 && i < c4) {            // W_hh pack region
      long ii = i - c3;                 // float4 index over W_hh [2048][512]
      int row = (int)(ii >> 7);         // = g*512 + j
      int c4i = (int)(ii & 127);
      int g = row >> 9, j = row & 511;
      float4 v = ((const float4*)W_hh)[ii];
      f16x2 p0; p0.x = (f16)v.x; p0.y = (f16)v.y;
      f16x2 p1; p1.x = (f16)v.z; p1.y = (f16)v.w;
      long k2a = 2 * (long)c4i;
      ((f16x2*)WhhP)[(k2a * 512 + j) * 4 + g] = p0;
      ((f16x2*)WhhP)[((k2a + 1) * 512 + j) * 4 + g] = p1;
      continue;
    }
    if (i >= c4 && i < c5) {            // U_a transpose-pack region
      long ii = i - c4;                 // float4 index over U_a [512][512]
      int k = (int)(ii >> 7);
      int j0 = (int)(ii & 127) * 4;
      float4 v = ((const float4*)U_a)[ii];
      f16x2 p0; p0.x = (f16)v.x; p0.y = (f16)v.y;
      f16x2 p1; p1.x = (f16)v.z; p1.y = (f16)v.w;
      ((f16x2*)UaT2)[(long)(j0 >> 1) * 512 + k] = p0;
      ((f16x2*)UaT2)[(long)((j0 >> 1) + 1) * 512 + k] = p1;
      continue;
    }
    const float4* s; f16x4* d; long j;
    if (i < c0)      { s = (const float4*)feat; d = (f16x4*)feat_h; j = i; }
    else if (i < c1) { s = (const float4*)W_a;  d = (f16x4*)W_a_h;  j = i - c0; }
    else if (i < c2) { s = (const float4*)W_ih; d = (f16x4*)W_ih_h; j = i - c1; }
    else if (i < c3) { s = (const float4*)fc_W; d = (f16x4*)fc_W_h; j = i - c2; }
    else if (i < c6) { s = (const float4*)Wh;   d = (f16x4*)Whc_h;  j = i - c5; }
    else if (i < c7) { s = (const float4*)Wc;   d = (f16x4*)(Whc_h + 1048576l); j = i - c6; }
    else {
      long jj = i - c7;                 // embedding gather region
      int n = (int)(jj >> 7), e4 = (int)(jj & 127);
      int tok = caps[n];
      s = (const float4*)(etab + (long)tok * 512); d = (f16x4*)(Aemb + (long)n * 512); j = e4;
    }
    float4 v = s[j];
    f16x4 o; o.x = (f16)v.x; o.y = (f16)v.y; o.z = (f16)v.z; o.w = (f16)v.w;
    d[j] = o;
  }
}

// ---------------- mean of features over P (from f16 feat) -> f16 [64,2048] ----------------
__global__ __launch_bounds__(256) void k_mean(const f16* __restrict__ feat_h,
                                              f16* __restrict__ mean_h) {
  int b = blockIdx.x;
  int e4 = blockIdx.y * 256 + threadIdx.x;
  const f16x4* src = (const f16x4*)(feat_h + (long)b * 49 * 2048) + e4;
  float s0 = 0.f, s1 = 0.f, s2 = 0.f, s3 = 0.f;
#pragma unroll 7
  for (int p = 0; p < 49; ++p) {
    f16x4 v = src[p * 512];
    s0 += (float)v.x; s1 += (float)v.y; s2 += (float)v.z; s3 += (float)v.w;
  }
  const float inv = 1.f / 49.f;
  f16x4 o; o.x = (f16)(s0 * inv); o.y = (f16)(s1 * inv); o.z = (f16)(s2 * inv); o.w = (f16)(s3 * inv);
  ((f16x4*)(mean_h + (long)b * 2048))[e4] = o;
}

// ---------------- h0/c0 split + biases + initial att2 partials (grid 64x4) ----------------
__global__ __launch_bounds__(512) void k_h0a2p(const float* __restrict__ Rh0,
                                               const float* __restrict__ bh,
                                               const float* __restrict__ bc,
                                               const f16* __restrict__ UaT2,
                                               f16* __restrict__ hA,
                                               float* __restrict__ c_state,
                                               float* __restrict__ a2pA) {
  __shared__ f16 hsl[128];
  const int b = blockIdx.x, q = blockIdx.y, tid = threadIdx.x;
  if (tid < 128) {
    int jg = q * 128 + tid;
    float hv = Rh0[(long)b * 1024 + jg] + bh[jg];
    c_state[(long)b * 512 + jg] = Rh0[(long)b * 1024 + 512 + jg] + bc[jg];
    f16 hf = (f16)hv;
    hsl[tid] = hf;
    hA[(long)b * 512 + jg] = hf;
  }
  __syncthreads();
  const unsigned* ua = (const unsigned*)UaT2 + (long)(q * 64) * 512 + tid;
  const f16x2* hv2 = (const f16x2*)hsl;
  float s0 = 0.f, s1 = 0.f;
#pragma unroll 8
  for (int j2 = 0; j2 < 64; j2 += 2) {
    s0 = fdot2f(hv2[j2], __builtin_bit_cast(f16x2, ua[(long)j2 * 512]), s0);
    s1 = fdot2f(hv2[j2 + 1], __builtin_bit_cast(f16x2, ua[(long)(j2 + 1) * 512]), s1);
  }
  a2pA[(long)b * 2048 + q * 512 + tid] = s0 + s1;
}

// ---------------- generic f16 MFMA GEMM (64x64 tile) — used only for h0/c0 (M=64) ----------
__global__ __launch_bounds__(256) void k_gemm(const f16* __restrict__ A, long lda,
                                              const f16* __restrict__ Bw, long ldb,
                                              float* __restrict__ Cout, long ldc,
                                              int K, int n_mtiles) {
  __shared__ f16 As[64][40];
  __shared__ f16 Bs[64][40];
  const int tid = threadIdx.x;
  const int lane = tid & 63, wave = tid >> 6;
  const int bid = blockIdx.x;
  const long m0 = (long)(bid % n_mtiles) * 64, n0 = (long)(bid / n_mtiles) * 64;
  const int lr = tid >> 2, lc = (tid & 3) * 8;
  const int wr = (wave >> 1) * 32, wc = (wave & 1) * 32;
  f32x4 acc[2][2] = {};
  const f16* Ap = A + (m0 + lr) * lda + lc;
  const f16* Bp = Bw + (n0 + lr) * ldb + lc;
  for (int k0 = 0; k0 < K; k0 += 32) {
    uint4 av = *(const uint4*)(Ap + k0);
    uint4 bv = *(const uint4*)(Bp + k0);
    __syncthreads();
    *(uint4*)&As[lr][lc] = av;
    *(uint4*)&Bs[lr][lc] = bv;
    __syncthreads();
#pragma unroll
    for (int mi = 0; mi < 2; ++mi) {
      f16x8 af = *(const f16x8*)&As[wr + mi * 16 + (lane & 15)][(lane >> 4) * 8];
#pragma unroll
      for (int ni = 0; ni < 2; ++ni) {
        f16x8 bf = *(const f16x8*)&Bs[wc + ni * 16 + (lane & 15)][(lane >> 4) * 8];
        acc[mi][ni] = __builtin_amdgcn_mfma_f32_16x16x32_f16(af, bf, acc[mi][ni], 0, 0, 0);
      }
    }
  }
#pragma unroll
  for (int mi = 0; mi < 2; ++mi)
#pragma unroll
    for (int ni = 0; ni < 2; ++ni) {
      int row_b = wr + mi * 16 + (lane >> 4) * 4;
      long gcol = n0 + wc + ni * 16 + (lane & 15);
#pragma unroll
      for (int r = 0; r < 4; ++r)
        Cout[(m0 + row_b + r) * ldc + gcol] = acc[mi][ni][r];
    }
}

// ---------------- 128x128 tile, BK=64, global_load_lds staging, XOR-swizzled LDS ------------
// XCD-bijective block swizzle (T1/m204): each XCD gets a contiguous wgid chunk -> contiguous
// n-stripes -> per-XCD L2-resident weight partition (fc_W: 8 x 4 MB slices).
__global__ __launch_bounds__(512) void k_gemm128b(const f16* __restrict__ A, long lda,
                                                  const f16* __restrict__ Bw, long ldb,
                                                  const float* __restrict__ bias1,
                                                  const float* __restrict__ bias2,
                                                  void* __restrict__ Cout, long ldc,
                                                  int K, int mode, int n_mtiles) {
  __shared__ f16 As[8192];   // [128][64] = 16 KB
  __shared__ f16 Bs[8192];
  const int tid = threadIdx.x, lane = tid & 63, wave = tid >> 6;
  const int wm = wave & 3, wn = wave >> 2;
  int bid;
  {
    const int nwg = (int)gridDim.x, ob = (int)blockIdx.x;
    const int qq = nwg >> 3, rr = nwg & 7;
    const int xcd = ob & 7, idx = ob >> 3;
    bid = (xcd < rr ? xcd * (qq + 1) : rr * (qq + 1) + (xcd - rr) * qq) + idx;
  }
  const long m0 = (long)(bid % n_mtiles) * 128, n0 = (long)(bid / n_mtiles) * 128;
  const int c0 = wave * 128 + lane, c1 = c0 + 64;
  const int r0 = c0 >> 3, s0 = (c0 & 7) ^ (r0 & 7);
  const int r1 = c1 >> 3, s1 = (c1 & 7) ^ (r1 & 7);
  const f16* gA0 = A + (m0 + r0) * lda + s0 * 8;
  const f16* gA1 = A + (m0 + r1) * lda + s1 * 8;
  const f16* gB0 = Bw + (n0 + r0) * ldb + s0 * 8;
  const f16* gB1 = Bw + (n0 + r1) * ldb + s1 * 8;
  f16* lA0 = As + (wave * 128) * 8;
  f16* lA1 = As + (wave * 128 + 64) * 8;
  f16* lB0 = Bs + (wave * 128) * 8;
  f16* lB1 = Bs + (wave * 128 + 64) * 8;
  f32x4 acc[2][4] = {};
  for (int k0 = 0; k0 < K; k0 += 64) {
    GLD16(gA0 + k0, lA0); GLD16(gA1 + k0, lA1);
    GLD16(gB0 + k0, lB0); GLD16(gB1 + k0, lB1);
    __syncthreads();
#pragma unroll
    for (int ks = 0; ks < 2; ++ks) {
      const int sp = (ks * 4 + (lane >> 4)) ^ (lane & 7);
#pragma unroll
      for (int mi = 0; mi < 2; ++mi) {
        const int rA = wm * 32 + mi * 16 + (lane & 15);
        f16x8 af = *(const f16x8*)(As + rA * 64 + sp * 8);
#pragma unroll
        for (int ni = 0; ni < 4; ++ni) {
          const int rB = wn * 64 + ni * 16 + (lane & 15);
          f16x8 bf = *(const f16x8*)(Bs + rB * 64 + sp * 8);
          acc[mi][ni] = __builtin_amdgcn_mfma_f32_16x16x32_f16(af, bf, acc[mi][ni], 0, 0, 0);
        }
      }
    }
    __syncthreads();
  }
#pragma unroll
  for (int mi = 0; mi < 2; ++mi)
#pragma unroll
    for (int ni = 0; ni < 4; ++ni) {
      int row_b = wm * 32 + mi * 16 + (lane >> 4) * 4;
      long gcol = n0 + wn * 64 + ni * 16 + (lane & 15);
      float badd = (bias1 ? bias1[gcol] : 0.f) + (bias2 ? bias2[gcol] : 0.f);
#pragma unroll
      for (int r = 0; r < 4; ++r) {
        long grow = m0 + row_b + r;
        float v = acc[mi][ni][r] + badd;
        if (mode == 0)      ((float*)Cout)[grow * ldc + gcol] = v;
        else if (mode == 1) ((f16*)Cout)[grow * ldc + gcol] = (f16)v;
        else                ((f16*)Cout)[grow * 2048 + ((gcol & 511) << 2) + (gcol >> 9)] = (f16)v;
      }
    }
}

// ---------------- fused full step, ONE dispatch per t, grid (64 b, 4 q) --------------------
// v3: all h-independent loads (first 16 W_hh uint4s, 13 featW uint2s, gates_x row)
// are issued BEFORE the phase-0 barrier so their L2 latency hides under launch ramp +
// h/att2 staging. Phase 1 stays barrier-free: W_hh stream ∥ scores VALU.
__global__ __launch_bounds__(512) void k_fstep(
    const f16* __restrict__ WhhP, const f16* __restrict__ UaT2,
    const float* __restrict__ b_Ua, const f16* __restrict__ att1,
    const float* __restrict__ va, const f16* __restrict__ featW4,
    const float* __restrict__ gates_x, float* __restrict__ c_state,
    const f16* __restrict__ hin, f16* __restrict__ hout,
    const float* __restrict__ a2pin, float* __restrict__ a2pout,
    f16* __restrict__ Hbuf, float* __restrict__ attw_out, int t) {
  __shared__ __align__(16) f16 hh[512];
  __shared__ float att2[512];
  __shared__ float sc[64];
  __shared__ float wl[49];
  __shared__ __align__(16) float gl4[4][128][4];   // per-w gate partials
  __shared__ __align__(16) f16 hsl[128];
  const int b = blockIdx.x, q = blockIdx.y, tid = threadIdx.x;
  const int lane = tid & 63, wave = tid >> 6;
  const long n = (long)b * 32 + t;
  const int jj = tid & 127, w = tid >> 7, jg = q * 128 + jj;

  // ---- pre-barrier: issue ALL h-independent loads ----
  const uint4* W4base = (const uint4*)WhhP + (long)(w * 64) * 512 + jg;
  uint4 wbuf[16];
#pragma unroll
  for (int i = 0; i < 16; ++i) wbuf[i] = W4base[(long)i * 512];
  uint2 fwv[13];
  {
    const f16* fw = featW4 + (long)(b * 49) * 2048 + q * 512 + jj * 4;
#pragma unroll
    for (int i = 0; i < 13; ++i) {
      int p = w + 4 * i; if (p > 48) p = 48;
      fwv[i] = *(const uint2*)(fw + (long)p * 2048);
    }
  }
  float g0, g1, g2, g3;
  if (w == 0) {               // fold gates_x into the w=0 partial
    const float* gx = gates_x + n * 2048;
    g0 = gx[jg]; g1 = gx[512 + jg]; g2 = gx[1024 + jg]; g3 = gx[1536 + jg];
  } else {
    g0 = g1 = g2 = g3 = 0.f;
  }

  // ---- phase 0: h + att2 assembly (1 barrier) ----
  hh[tid] = hin[(long)b * 512 + tid];
  const float* ap = a2pin + (long)b * 2048;
  att2[tid] = b_Ua[tid] + ap[tid] + ap[512 + tid] + ap[1024 + tid] + ap[1536 + tid];
  __syncthreads();

  // ---- phase 1 (barrier-free): W_hh gate partials ∥ scores ----
  {
    const f16x2* hp = (const f16x2*)hh;
#pragma unroll
    for (int i = 0; i < 16; ++i) {       // consume prefetched
      f16x2 hv = hp[w * 64 + i];
      g0 = fdot2f(hv, __builtin_bit_cast(f16x2, wbuf[i].x), g0);
      g1 = fdot2f(hv, __builtin_bit_cast(f16x2, wbuf[i].y), g1);
      g2 = fdot2f(hv, __builtin_bit_cast(f16x2, wbuf[i].z), g2);
      g3 = fdot2f(hv, __builtin_bit_cast(f16x2, wbuf[i].w), g3);
    }
#pragma unroll 8
    for (int i = 16; i < 64; ++i) {      // stream the rest
      uint4 wv4 = W4base[(long)i * 512];
      f16x2 hv = hp[w * 64 + i];
      g0 = fdot2f(hv, __builtin_bit_cast(f16x2, wv4.x), g0);
      g1 = fdot2f(hv, __builtin_bit_cast(f16x2, wv4.y), g1);
      g2 = fdot2f(hv, __builtin_bit_cast(f16x2, wv4.z), g2);
      g3 = fdot2f(hv, __builtin_bit_cast(f16x2, wv4.w), g3);
    }
  }
  // scores: wave w' handles p = w', w'+8, ... (overlaps other waves' W_hh memory)
  for (int p = wave; p < 49; p += 8) {
    const f16* arow = att1 + ((long)b * 49 + p) * 512;
    float s = 0.f;
#pragma unroll
    for (int kk = 0; kk < 8; ++kk) {
      int k = lane + kk * 64;
      float x = (float)arow[k] + att2[k];
      float e = __expf(2.f * x);
      s += va[k] * (1.f - 2.f / (e + 1.f));
    }
#pragma unroll
    for (int off = 32; off; off >>= 1) s += __shfl_xor(s, off);
    if (lane == 0) sc[p] = s;
  }
  __syncthreads();

  // ---- phase 2: softmax over P=49 (wave 0; b_va softmax-invariant) ----
  if (wave == 0) {
    float s = (lane < 49) ? sc[lane] : -1e30f;
    float m = s;
#pragma unroll
    for (int off = 32; off; off >>= 1) m = fmaxf(m, __shfl_xor(m, off));
    float e = (lane < 49) ? __expf(s - m) : 0.f;
    float sum = e;
#pragma unroll
    for (int off = 32; off; off >>= 1) sum += __shfl_xor(sum, off);
    float wv = e / sum;
    if (lane < 49) {
      wl[lane] = wv;
      if (q == 0) attw_out[n * 49 + lane] = wv;
    }
  }
  __syncthreads();

  // ---- phase 3: ctx accumulation from prefetched registers ----
#pragma unroll
  for (int i = 0; i < 13; ++i) {
    int p = w + 4 * i;
    if (p < 49) {
      float wp = wl[p];
      f16x2 aa = __builtin_bit_cast(f16x2, fwv[i].x);
      f16x2 bb = __builtin_bit_cast(f16x2, fwv[i].y);
      g0 += wp * (float)aa.x; g1 += wp * (float)aa.y;
      g2 += wp * (float)bb.x; g3 += wp * (float)bb.y;
    }
  }
  {
    float4 gv4; gv4.x = g0; gv4.y = g1; gv4.z = g2; gv4.w = g3;
    *(float4*)&gl4[w][jj][0] = gv4;
  }
  __syncthreads();

  // ---- phase 4: LSTM pointwise (tid < 128) ----
  if (tid < 128) {
    int jgl = q * 128 + tid;
    float G0 = gl4[0][tid][0] + gl4[1][tid][0] + gl4[2][tid][0] + gl4[3][tid][0];
    float G1 = gl4[0][tid][1] + gl4[1][tid][1] + gl4[2][tid][1] + gl4[3][tid][1];
    float G2 = gl4[0][tid][2] + gl4[1][tid][2] + gl4[2][tid][2] + gl4[3][tid][2];
    float G3 = gl4[0][tid][3] + gl4[1][tid][3] + gl4[2][tid][3] + gl4[3][tid][3];
    float c = c_state[(long)b * 512 + jgl];
    float iv = 1.f / (1.f + __expf(-G0));
    float fv = 1.f / (1.f + __expf(-G1));
    float e2 = __expf(2.f * G2); float gg = 1.f - 2.f / (e2 + 1.f);
    float ov = 1.f / (1.f + __expf(-G3));
    c = fv * c + iv * gg;
    float e3 = __expf(2.f * c); float tc = 1.f - 2.f / (e3 + 1.f);
    float hn = ov * tc;
    c_state[(long)b * 512 + jgl] = c;
    f16 hf = (f16)hn;
    hsl[tid] = hf;
    hout[(long)b * 512 + jgl] = hf;
    Hbuf[n * 512 + jgl] = hf;
  }
  __syncthreads();

  // ---- phase 5: att2 partial for NEXT step (UaT2 lanes-contiguous) ----
  {
    const unsigned* ua = (const unsigned*)UaT2 + (long)(q * 64) * 512 + tid;
    const f16x2* hv2 = (const f16x2*)hsl;
    float s0 = 0.f, s1 = 0.f;
#pragma unroll 8
    for (int j2 = 0; j2 < 64; j2 += 2) {
      s0 = fdot2f(hv2[j2], __builtin_bit_cast(f16x2, ua[(long)j2 * 512]), s0);
      s1 = fdot2f(hv2[j2 + 1], __builtin_bit_cast(f16x2, ua[(long)(j2 + 1) * 512]), s1);
    }
    a2pout[(long)b * 2048 + q * 512 + tid] = s0 + s1;
  }
}

extern "C" void kernel_launch(void* const* d_in, const int* in_sizes, int n_in,
                              void* d_out, int out_size, void* d_ws, size_t ws_size,
                              hipStream_t stream) {
  const int*   caps = (const int*)d_in[0];
  const float* feat = (const float*)d_in[1];
  const float* etab = (const float*)d_in[2];
  const float* W_a  = (const float*)d_in[3];
  const float* b_Wa = (const float*)d_in[4];
  const float* U_a  = (const float*)d_in[5];
  const float* b_Ua = (const float*)d_in[6];
  const float* v_a  = (const float*)d_in[7];
  /* d_in[8] b_va: softmax-invariant, unused */
  const float* W_ih = (const float*)d_in[9];
  const float* b_ih = (const float*)d_in[10];
  const float* W_hh = (const float*)d_in[11];
  const float* b_hh = (const float*)d_in[12];
  const float* fc_W = (const float*)d_in[13];
  const float* fc_b = (const float*)d_in[14];
  const float* Wh   = (const float*)d_in[15];
  const float* bh   = (const float*)d_in[16];
  const float* Wc   = (const float*)d_in[17];
  const float* bc   = (const float*)d_in[18];

  char* ws = (char*)d_ws;
  size_t off = 0;
  auto alloc = [&](size_t bytes) { void* p = ws + off; off += (bytes + 255) & ~(size_t)255; return p; };
  f16* feat_h  = (f16*)alloc(6553600ull * 2);   // [3200,2048] (3136 valid rows)
  f16* W_a_h   = (f16*)alloc(1048576ull * 2);   // H*F
  f16* W_ih_h  = (f16*)alloc(5242880ull * 2);   // 4H*(E+F)
  f16* fc_W_h  = (f16*)alloc(16384000ull * 2);  // V*H
  f16* Aemb    = (f16*)alloc(1048576ull * 2);   // B*S*E
  f16* WhhP    = (f16*)alloc(1048576ull * 2);   // W_hh gate-pack (uint4 @ [k2*512+j])
  f16* UaT2    = (f16*)alloc(262144ull * 2);    // U_a transpose-pack [j2][k] f16x2
  f16* Whc_h   = (f16*)alloc(2097152ull * 2);   // [Wh;Wc] = [1024,2048] f16
  f16* mean_h  = (f16*)alloc(131072ull * 2);    // [64,2048] mean features f16
  f16* att1_h  = (f16*)alloc(1638400ull * 2);   // [3200,512] (3136 valid)
  f16* featW4  = (f16*)alloc(6553600ull * 2);   // [3200,2048] g-interleaved (3136 valid)
  float* gates_x = (float*)alloc(4194304ull * 4); // B*S*4H
  float* Rh0   = (float*)alloc(65536ull * 4);   // [64,1024] h0/c0 GEMM out
  f16* hA      = (f16*)alloc(32768ull * 2);     // h ping
  f16* hB      = (f16*)alloc(32768ull * 2);     // h pong
  float* a2pA  = (float*)alloc(131072ull * 4);  // att2 partials ping [64][4][512]
  float* a2pB  = (float*)alloc(131072ull * 4);  // att2 partials pong
  float* c_state = (float*)alloc(32768ull * 4); // [64,512] c state
  f16* Hbuf    = (f16*)alloc(1048576ull * 2);   // B*S*H
  (void)ws_size; (void)in_sizes; (void)n_in; (void)out_size;

  float* out_logits = (float*)d_out;
  float* out_attw   = out_logits + 65536000ull;

  // Phase A: fused converts + packs + embedding gather, then precompute
  k_prep<<<4096, 256, 0, stream>>>(feat, W_a, W_ih, fc_W, W_hh, U_a, Wh, Wc, caps, etab,
                                   feat_h, W_a_h, W_ih_h, fc_W_h, WhhP, UaT2, Whc_h, Aemb);
  k_mean<<<dim3(64, 2), 256, 0, stream>>>(feat_h, mean_h);

  // h0/c0: [64,1024] = mean_h @ [Wh;Wc]^T  K=2048 -> f32 ; then split + initial att2 partials
  k_gemm<<<16, 256, 0, stream>>>(mean_h, 2048, Whc_h, 2048, Rh0, 1024, 2048, 1);
  k_h0a2p<<<dim3(64, 4), 512, 0, stream>>>(Rh0, bh, bc, UaT2, hA, c_state, a2pA);

  // att1 = features @ W_a^T + b_Wa         [3200,512]  K=2048 -> f16   (25 m x 4 n)
  k_gemm128b<<<25 * 4, 512, 0, stream>>>(feat_h, 2048, W_a_h, 2048,
                                         b_Wa, nullptr, att1_h, 512, 2048, 1, 25);
  // featW = features @ W_ih[:,E:]^T        [3200,2048] K=2048 -> f16 g-interleaved (25 x 16)
  k_gemm128b<<<25 * 16, 512, 0, stream>>>(feat_h, 2048, W_ih_h + 512, 2560,
                                          nullptr, nullptr, featW4, 0, 2048, 2, 25);
  // gates_x = embed @ W_ih[:,:E]^T + b_ih + b_hh   [2048,2048] K=512 -> f32 (16 x 16)
  k_gemm128b<<<16 * 16, 512, 0, stream>>>(Aemb, 512, W_ih_h, 2560,
                                          b_ih, b_hh, gates_x, 2048, 512, 0, 16);

  // Phase B: sequential recurrence — ONE dispatch per step (ping-pong h and att2p)
  for (int t = 0; t < 32; ++t) {
    const f16* hin = (t & 1) ? hB : hA;
    f16* hout = (t & 1) ? hA : hB;
    const float* a2i = (t & 1) ? a2pB : a2pA;
    float* a2o = (t & 1) ? a2pA : a2pB;
    k_fstep<<<dim3(64, 4), 512, 0, stream>>>(WhhP, UaT2, b_Ua, att1_h, v_a, featW4,
                                             gates_x, c_state, hin, hout, a2i, a2o,
                                             Hbuf, out_attw, t);
  }

  // Phase C: logits = H @ fc_W^T + fc_b    [2048,32000] K=512 -> f32 (16 m x 250 n)
  k_gemm128b<<<16 * 250, 512, 0, stream>>>(Hbuf, 512, fc_W_h, 512,
                                           fc_b, nullptr, out_logits, 32000, 512, 0, 16);
}

// Round 14
// 847.398 us; speedup vs baseline: 1.0003x; 1.0003x over previous
//
#include <hip/hip_runtime.h>
#include <hip/hip_fp16.h>

typedef _Float16 f16;
typedef _Float16 f16x2 __attribute__((ext_vector_type(2)));
typedef _Float16 f16x4 __attribute__((ext_vector_type(4)));
typedef _Float16 f16x8 __attribute__((ext_vector_type(8)));
typedef float    f32x4 __attribute__((ext_vector_type(4)));

// Problem constants: B=64, S=32, P=49, F=2048, E=512, H=512, V=32000
// M=3136 (B*P) padded to 3200 for 128-row tiles.

#define GLD16(g, l)                                                        \
  __builtin_amdgcn_global_load_lds(                                        \
      (const __attribute__((address_space(1))) void*)(g),                  \
      (__attribute__((address_space(3))) void*)(l), 16, 0, 0)

static __device__ __forceinline__ float fdot2f(f16x2 a, f16x2 b, float c) {
#if __has_builtin(__builtin_amdgcn_fdot2)
  return __builtin_amdgcn_fdot2(a, b, c, false);
#else
  return c + (float)a.x * (float)b.x + (float)a.y * (float)b.y;
#endif
}

// ---------------- fused converts + packs + embedding gather (ONE dispatch) ----------------
// WhhP pack (R1-proven): uint4 at [k2*512 + j] = 4 gates x f16-pair (W_hh[g*512+j][2k2..2k2+1])
// UaT2 pack: f16x2 at dword [j2*512 + k] = (U_a[k][2j2], U_a[k][2j2+1])
__global__ __launch_bounds__(256) void k_prep(
    const float* __restrict__ feat, const float* __restrict__ W_a,
    const float* __restrict__ W_ih, const float* __restrict__ fc_W,
    const float* __restrict__ W_hh, const float* __restrict__ U_a,
    const float* __restrict__ Wh, const float* __restrict__ Wc,
    const int* __restrict__ caps, const float* __restrict__ etab,
    f16* __restrict__ feat_h, f16* __restrict__ W_a_h,
    f16* __restrict__ W_ih_h, f16* __restrict__ fc_W_h,
    f16* __restrict__ WhhP, f16* __restrict__ UaT2,
    f16* __restrict__ Whc_h, f16* __restrict__ Aemb) {
  const long c0 = 1605632;              // feat      (6422528 f32 /4)
  const long c1 = c0 + 262144;          // W_a
  const long c2 = c1 + 1310720;         // W_ih
  const long c3 = c2 + 4096000;         // fc_W
  const long c4 = c3 + 262144;          // W_hh -> WhhP pack
  const long c5 = c4 + 65536;           // U_a  -> UaT2 pack
  const long c6 = c5 + 262144;          // Wh   -> Whc rows 0..511
  const long c7 = c6 + 262144;          // Wc   -> Whc rows 512..1023
  const long c8 = c7 + 262144;          // embed: 2048 rows x 128 f16x4 chunks
  long i = (long)blockIdx.x * 256 + threadIdx.x;
  const long stride = (long)gridDim.x * 256;
  for (; i < c8; i += stride) {
    if (i >= c3 && i < c4) {            // W_hh pack region
      long ii = i - c3;                 // float4 index over W_hh [2048][512]
      int row = (int)(ii >> 7);         // = g*512 + j
      int c4i = (int)(ii & 127);
      int g = row >> 9, j = row & 511;
      float4 v = ((const float4*)W_hh)[ii];
      f16x2 p0; p0.x = (f16)v.x; p0.y = (f16)v.y;
      f16x2 p1; p1.x = (f16)v.z; p1.y = (f16)v.w;
      long k2a = 2 * (long)c4i;
      ((f16x2*)WhhP)[(k2a * 512 + j) * 4 + g] = p0;
      ((f16x2*)WhhP)[((k2a + 1) * 512 + j) * 4 + g] = p1;
      continue;
    }
    if (i >= c4 && i < c5) {            // U_a transpose-pack region
      long ii = i - c4;                 // float4 index over U_a [512][512]
      int k = (int)(ii >> 7);
      int j0 = (int)(ii & 127) * 4;
      float4 v = ((const float4*)U_a)[ii];
      f16x2 p0; p0.x = (f16)v.x; p0.y = (f16)v.y;
      f16x2 p1; p1.x = (f16)v.z; p1.y = (f16)v.w;
      ((f16x2*)UaT2)[(long)(j0 >> 1) * 512 + k] = p0;
      ((f16x2*)UaT2)[(long)((j0 >> 1) + 1) * 512 + k] = p1;
      continue;
    }
    const float4* s; f16x4* d; long j;
    if (i < c0)      { s = (const float4*)feat; d = (f16x4*)feat_h; j = i; }
    else if (i < c1) { s = (const float4*)W_a;  d = (f16x4*)W_a_h;  j = i - c0; }
    else if (i < c2) { s = (const float4*)W_ih; d = (f16x4*)W_ih_h; j = i - c1; }
    else if (i < c3) { s = (const float4*)fc_W; d = (f16x4*)fc_W_h; j = i - c2; }
    else if (i < c6) { s = (const float4*)Wh;   d = (f16x4*)Whc_h;  j = i - c5; }
    else if (i < c7) { s = (const float4*)Wc;   d = (f16x4*)(Whc_h + 1048576l); j = i - c6; }
    else {
      long jj = i - c7;                 // embedding gather region
      int n = (int)(jj >> 7), e4 = (int)(jj & 127);
      int tok = caps[n];
      s = (const float4*)(etab + (long)tok * 512); d = (f16x4*)(Aemb + (long)n * 512); j = e4;
    }
    float4 v = s[j];
    f16x4 o; o.x = (f16)v.x; o.y = (f16)v.y; o.z = (f16)v.z; o.w = (f16)v.w;
    d[j] = o;
  }
}

// ---------------- mean of features over P (from f16 feat) -> f16 [64,2048] ----------------
__global__ __launch_bounds__(256) void k_mean(const f16* __restrict__ feat_h,
                                              f16* __restrict__ mean_h) {
  int b = blockIdx.x;
  int e4 = blockIdx.y * 256 + threadIdx.x;
  const f16x4* src = (const f16x4*)(feat_h + (long)b * 49 * 2048) + e4;
  float s0 = 0.f, s1 = 0.f, s2 = 0.f, s3 = 0.f;
#pragma unroll 7
  for (int p = 0; p < 49; ++p) {
    f16x4 v = src[p * 512];
    s0 += (float)v.x; s1 += (float)v.y; s2 += (float)v.z; s3 += (float)v.w;
  }
  const float inv = 1.f / 49.f;
  f16x4 o; o.x = (f16)(s0 * inv); o.y = (f16)(s1 * inv); o.z = (f16)(s2 * inv); o.w = (f16)(s3 * inv);
  ((f16x4*)(mean_h + (long)b * 2048))[e4] = o;
}

// ---------------- h0/c0 split + biases + initial att2 partials (grid 64x4) ----------------
__global__ __launch_bounds__(512) void k_h0a2p(const float* __restrict__ Rh0,
                                               const float* __restrict__ bh,
                                               const float* __restrict__ bc,
                                               const f16* __restrict__ UaT2,
                                               f16* __restrict__ hA,
                                               float* __restrict__ c_state,
                                               float* __restrict__ a2pA) {
  __shared__ f16 hsl[128];
  const int b = blockIdx.x, q = blockIdx.y, tid = threadIdx.x;
  if (tid < 128) {
    int jg = q * 128 + tid;
    float hv = Rh0[(long)b * 1024 + jg] + bh[jg];
    c_state[(long)b * 512 + jg] = Rh0[(long)b * 1024 + 512 + jg] + bc[jg];
    f16 hf = (f16)hv;
    hsl[tid] = hf;
    hA[(long)b * 512 + jg] = hf;
  }
  __syncthreads();
  const unsigned* ua = (const unsigned*)UaT2 + (long)(q * 64) * 512 + tid;
  const f16x2* hv2 = (const f16x2*)hsl;
  float s0 = 0.f, s1 = 0.f;
#pragma unroll 8
  for (int j2 = 0; j2 < 64; j2 += 2) {
    s0 = fdot2f(hv2[j2], __builtin_bit_cast(f16x2, ua[(long)j2 * 512]), s0);
    s1 = fdot2f(hv2[j2 + 1], __builtin_bit_cast(f16x2, ua[(long)(j2 + 1) * 512]), s1);
  }
  a2pA[(long)b * 2048 + q * 512 + tid] = s0 + s1;
}

// ---------------- generic f16 MFMA GEMM (64x64 tile) — used only for h0/c0 (M=64) ----------
__global__ __launch_bounds__(256) void k_gemm(const f16* __restrict__ A, long lda,
                                              const f16* __restrict__ Bw, long ldb,
                                              float* __restrict__ Cout, long ldc,
                                              int K, int n_mtiles) {
  __shared__ f16 As[64][40];
  __shared__ f16 Bs[64][40];
  const int tid = threadIdx.x;
  const int lane = tid & 63, wave = tid >> 6;
  const int bid = blockIdx.x;
  const long m0 = (long)(bid % n_mtiles) * 64, n0 = (long)(bid / n_mtiles) * 64;
  const int lr = tid >> 2, lc = (tid & 3) * 8;
  const int wr = (wave >> 1) * 32, wc = (wave & 1) * 32;
  f32x4 acc[2][2] = {};
  const f16* Ap = A + (m0 + lr) * lda + lc;
  const f16* Bp = Bw + (n0 + lr) * ldb + lc;
  for (int k0 = 0; k0 < K; k0 += 32) {
    uint4 av = *(const uint4*)(Ap + k0);
    uint4 bv = *(const uint4*)(Bp + k0);
    __syncthreads();
    *(uint4*)&As[lr][lc] = av;
    *(uint4*)&Bs[lr][lc] = bv;
    __syncthreads();
#pragma unroll
    for (int mi = 0; mi < 2; ++mi) {
      f16x8 af = *(const f16x8*)&As[wr + mi * 16 + (lane & 15)][(lane >> 4) * 8];
#pragma unroll
      for (int ni = 0; ni < 2; ++ni) {
        f16x8 bf = *(const f16x8*)&Bs[wc + ni * 16 + (lane & 15)][(lane >> 4) * 8];
        acc[mi][ni] = __builtin_amdgcn_mfma_f32_16x16x32_f16(af, bf, acc[mi][ni], 0, 0, 0);
      }
    }
  }
#pragma unroll
  for (int mi = 0; mi < 2; ++mi)
#pragma unroll
    for (int ni = 0; ni < 2; ++ni) {
      int row_b = wr + mi * 16 + (lane >> 4) * 4;
      long gcol = n0 + wc + ni * 16 + (lane & 15);
#pragma unroll
      for (int r = 0; r < 4; ++r)
        Cout[(m0 + row_b + r) * ldc + gcol] = acc[mi][ni][r];
    }
}

// ---------------- 128x128 tile, BK=64, global_load_lds staging, XOR-swizzled LDS ------------
// (no XCD swizzle — R13 measured it net-negative on L3-resident weights)
__global__ __launch_bounds__(512) void k_gemm128b(const f16* __restrict__ A, long lda,
                                                  const f16* __restrict__ Bw, long ldb,
                                                  const float* __restrict__ bias1,
                                                  const float* __restrict__ bias2,
                                                  void* __restrict__ Cout, long ldc,
                                                  int K, int mode, int n_mtiles) {
  __shared__ f16 As[8192];   // [128][64] = 16 KB
  __shared__ f16 Bs[8192];
  const int tid = threadIdx.x, lane = tid & 63, wave = tid >> 6;
  const int wm = wave & 3, wn = wave >> 2;
  const int bid = blockIdx.x;
  const long m0 = (long)(bid % n_mtiles) * 128, n0 = (long)(bid / n_mtiles) * 128;
  const int c0 = wave * 128 + lane, c1 = c0 + 64;
  const int r0 = c0 >> 3, s0 = (c0 & 7) ^ (r0 & 7);
  const int r1 = c1 >> 3, s1 = (c1 & 7) ^ (r1 & 7);
  const f16* gA0 = A + (m0 + r0) * lda + s0 * 8;
  const f16* gA1 = A + (m0 + r1) * lda + s1 * 8;
  const f16* gB0 = Bw + (n0 + r0) * ldb + s0 * 8;
  const f16* gB1 = Bw + (n0 + r1) * ldb + s1 * 8;
  f16* lA0 = As + (wave * 128) * 8;
  f16* lA1 = As + (wave * 128 + 64) * 8;
  f16* lB0 = Bs + (wave * 128) * 8;
  f16* lB1 = Bs + (wave * 128 + 64) * 8;
  f32x4 acc[2][4] = {};
  for (int k0 = 0; k0 < K; k0 += 64) {
    GLD16(gA0 + k0, lA0); GLD16(gA1 + k0, lA1);
    GLD16(gB0 + k0, lB0); GLD16(gB1 + k0, lB1);
    __syncthreads();
#pragma unroll
    for (int ks = 0; ks < 2; ++ks) {
      const int sp = (ks * 4 + (lane >> 4)) ^ (lane & 7);
#pragma unroll
      for (int mi = 0; mi < 2; ++mi) {
        const int rA = wm * 32 + mi * 16 + (lane & 15);
        f16x8 af = *(const f16x8*)(As + rA * 64 + sp * 8);
#pragma unroll
        for (int ni = 0; ni < 4; ++ni) {
          const int rB = wn * 64 + ni * 16 + (lane & 15);
          f16x8 bf = *(const f16x8*)(Bs + rB * 64 + sp * 8);
          acc[mi][ni] = __builtin_amdgcn_mfma_f32_16x16x32_f16(af, bf, acc[mi][ni], 0, 0, 0);
        }
      }
    }
    __syncthreads();
  }
#pragma unroll
  for (int mi = 0; mi < 2; ++mi)
#pragma unroll
    for (int ni = 0; ni < 4; ++ni) {
      int row_b = wm * 32 + mi * 16 + (lane >> 4) * 4;
      long gcol = n0 + wn * 64 + ni * 16 + (lane & 15);
      float badd = (bias1 ? bias1[gcol] : 0.f) + (bias2 ? bias2[gcol] : 0.f);
#pragma unroll
      for (int r = 0; r < 4; ++r) {
        long grow = m0 + row_b + r;
        float v = acc[mi][ni][r] + badd;
        if (mode == 0)      ((float*)Cout)[grow * ldc + gcol] = v;
        else if (mode == 1) ((f16*)Cout)[grow * ldc + gcol] = (f16)v;
        else                ((f16*)Cout)[grow * 2048 + ((gcol & 511) << 2) + (gcol >> 9)] = (f16)v;
      }
    }
}

// ---------------- 128x256 tile, BK=64: 32 MFMA per barrier pair (2x the 128x128 kernel) -----
// Combined LDS buffer: 384 rows (A=0..127, B=128..383) x 8 slots of 16B, slot ^= (row&7).
// 512 threads / 8 waves as 2m x 4n; per-wave output 64x64 (16 x f32x4 acc).
__global__ __launch_bounds__(512) void k_gemm256(const f16* __restrict__ A, long lda,
                                                 const f16* __restrict__ Bw, long ldb,
                                                 const float* __restrict__ bias1,
                                                 const float* __restrict__ bias2,
                                                 void* __restrict__ Cout, long ldc,
                                                 int K, int mode, int n_mtiles) {
  __shared__ f16 S[3072 * 8];          // 48 KB
  const int tid = threadIdx.x, lane = tid & 63, wave = tid >> 6;
  const int wm = wave & 1, wn = wave >> 1;
  const int bid = blockIdx.x;
  const long m0 = (long)(bid % n_mtiles) * 128, n0 = (long)(bid / n_mtiles) * 256;
  // staging: 6 chunks/thread; chunk c = i*512 + wave*64 + lane; row = c>>3 (0..383)
  const f16* gsrc[6];
  f16* ldst[6];
#pragma unroll
  for (int i = 0; i < 6; ++i) {
    int c = i * 512 + wave * 64 + lane;
    int row = c >> 3;
    int slot = (c & 7) ^ (row & 7);
    gsrc[i] = (row < 128) ? (A + (m0 + row) * lda + slot * 8)
                          : (Bw + (n0 + (row - 128)) * ldb + slot * 8);
    ldst[i] = S + (long)(i * 512 + wave * 64) * 8;   // wave-uniform base; HW adds lane*16
  }
  f32x4 acc[4][4] = {};
  for (int k0 = 0; k0 < K; k0 += 64) {
#pragma unroll
    for (int i = 0; i < 6; ++i) GLD16(gsrc[i] + k0, ldst[i]);
    __syncthreads();
#pragma unroll
    for (int kk = 0; kk < 2; ++kk) {
      f16x8 bfv[4];
#pragma unroll
      for (int ni = 0; ni < 4; ++ni) {
        const int rB = 128 + wn * 64 + ni * 16 + (lane & 15);
        const int spB = (kk * 4 + (lane >> 4)) ^ (rB & 7);
        bfv[ni] = *(const f16x8*)(S + (long)(rB * 8 + spB) * 8);
      }
#pragma unroll
      for (int mi = 0; mi < 4; ++mi) {
        const int rA = wm * 64 + mi * 16 + (lane & 15);
        const int spA = (kk * 4 + (lane >> 4)) ^ (rA & 7);
        f16x8 af = *(const f16x8*)(S + (long)(rA * 8 + spA) * 8);
#pragma unroll
        for (int ni = 0; ni < 4; ++ni)
          acc[mi][ni] = __builtin_amdgcn_mfma_f32_16x16x32_f16(af, bfv[ni], acc[mi][ni], 0, 0, 0);
      }
    }
    __syncthreads();
  }
#pragma unroll
  for (int mi = 0; mi < 4; ++mi)
#pragma unroll
    for (int ni = 0; ni < 4; ++ni) {
      int row_b = wm * 64 + mi * 16 + (lane >> 4) * 4;
      long gcol = n0 + wn * 64 + ni * 16 + (lane & 15);
      float badd = (bias1 ? bias1[gcol] : 0.f) + (bias2 ? bias2[gcol] : 0.f);
#pragma unroll
      for (int r = 0; r < 4; ++r) {
        long grow = m0 + row_b + r;
        float v = acc[mi][ni][r] + badd;
        if (mode == 0)      ((float*)Cout)[grow * ldc + gcol] = v;
        else if (mode == 1) ((f16*)Cout)[grow * ldc + gcol] = (f16)v;
        else                ((f16*)Cout)[grow * 2048 + ((gcol & 511) << 2) + (gcol >> 9)] = (f16)v;
      }
    }
}

// ---------------- fused full step, ONE dispatch per t, grid (64 b, 4 q) --------------------
// R12 version (phase-overlap, no W_hh reg-prefetch — R13 measured that net-negative).
__global__ __launch_bounds__(512) void k_fstep(
    const f16* __restrict__ WhhP, const f16* __restrict__ UaT2,
    const float* __restrict__ b_Ua, const f16* __restrict__ att1,
    const float* __restrict__ va, const f16* __restrict__ featW4,
    const float* __restrict__ gates_x, float* __restrict__ c_state,
    const f16* __restrict__ hin, f16* __restrict__ hout,
    const float* __restrict__ a2pin, float* __restrict__ a2pout,
    f16* __restrict__ Hbuf, float* __restrict__ attw_out, int t) {
  __shared__ __align__(16) f16 hh[512];
  __shared__ float att2[512];
  __shared__ float sc[64];
  __shared__ float wl[49];
  __shared__ __align__(16) float gl4[4][128][4];   // per-w gate partials
  __shared__ __align__(16) f16 hsl[128];
  const int b = blockIdx.x, q = blockIdx.y, tid = threadIdx.x;
  const int lane = tid & 63, wave = tid >> 6;
  const long n = (long)b * 32 + t;
  const int jj = tid & 127, w = tid >> 7, jg = q * 128 + jj;

  // ---- phase 0: h + att2 assembly (1 barrier) ----
  hh[tid] = hin[(long)b * 512 + tid];
  const float* ap = a2pin + (long)b * 2048;
  att2[tid] = b_Ua[tid] + ap[tid] + ap[512 + tid] + ap[1024 + tid] + ap[1536 + tid];
  __syncthreads();

  // ---- phase 1 (barrier-free): W_hh gate partials ∥ featW prefetch ∥ scores ----
  float g0, g1, g2, g3;
  if (w == 0) {               // fold gates_x into the w=0 partial
    const float* gx = gates_x + n * 2048;
    g0 = gx[jg]; g1 = gx[512 + jg]; g2 = gx[1024 + jg]; g3 = gx[1536 + jg];
  } else {
    g0 = g1 = g2 = g3 = 0.f;
  }
  uint2 fwv[13];
  {
    const f16* fw = featW4 + (long)(b * 49) * 2048 + q * 512 + jj * 4;
#pragma unroll
    for (int i = 0; i < 13; ++i) {
      int p = w + 4 * i; if (p > 48) p = 48;
      fwv[i] = *(const uint2*)(fw + (long)p * 2048);
    }
  }
  {
    const uint4* W4 = (const uint4*)WhhP;
    const f16x2* hp = (const f16x2*)hh;
#pragma unroll 8
    for (int k2 = w * 64; k2 < w * 64 + 64; ++k2) {
      uint4 wv4 = W4[(long)k2 * 512 + jg];
      f16x2 hv = hp[k2];
      g0 = fdot2f(hv, __builtin_bit_cast(f16x2, wv4.x), g0);
      g1 = fdot2f(hv, __builtin_bit_cast(f16x2, wv4.y), g1);
      g2 = fdot2f(hv, __builtin_bit_cast(f16x2, wv4.z), g2);
      g3 = fdot2f(hv, __builtin_bit_cast(f16x2, wv4.w), g3);
    }
  }
  // scores: wave w' handles p = w', w'+8, ... (overlaps other waves' W_hh memory)
  for (int p = wave; p < 49; p += 8) {
    const f16* arow = att1 + ((long)b * 49 + p) * 512;
    float s = 0.f;
#pragma unroll
    for (int kk = 0; kk < 8; ++kk) {
      int k = lane + kk * 64;
      float x = (float)arow[k] + att2[k];
      float e = __expf(2.f * x);
      s += va[k] * (1.f - 2.f / (e + 1.f));
    }
#pragma unroll
    for (int off = 32; off; off >>= 1) s += __shfl_xor(s, off);
    if (lane == 0) sc[p] = s;
  }
  __syncthreads();

  // ---- phase 2: softmax over P=49 (wave 0; b_va softmax-invariant) ----
  if (wave == 0) {
    float s = (lane < 49) ? sc[lane] : -1e30f;
    float m = s;
#pragma unroll
    for (int off = 32; off; off >>= 1) m = fmaxf(m, __shfl_xor(m, off));
    float e = (lane < 49) ? __expf(s - m) : 0.f;
    float sum = e;
#pragma unroll
    for (int off = 32; off; off >>= 1) sum += __shfl_xor(sum, off);
    float wv = e / sum;
    if (lane < 49) {
      wl[lane] = wv;
      if (q == 0) attw_out[n * 49 + lane] = wv;
    }
  }
  __syncthreads();

  // ---- phase 3: ctx accumulation from prefetched registers ----
#pragma unroll
  for (int i = 0; i < 13; ++i) {
    int p = w + 4 * i;
    if (p < 49) {
      float wp = wl[p];
      f16x2 aa = __builtin_bit_cast(f16x2, fwv[i].x);
      f16x2 bb = __builtin_bit_cast(f16x2, fwv[i].y);
      g0 += wp * (float)aa.x; g1 += wp * (float)aa.y;
      g2 += wp * (float)bb.x; g3 += wp * (float)bb.y;
    }
  }
  {
    float4 gv4; gv4.x = g0; gv4.y = g1; gv4.z = g2; gv4.w = g3;
    *(float4*)&gl4[w][jj][0] = gv4;
  }
  __syncthreads();

  // ---- phase 4: LSTM pointwise (tid < 128) ----
  if (tid < 128) {
    int jgl = q * 128 + tid;
    float G0 = gl4[0][tid][0] + gl4[1][tid][0] + gl4[2][tid][0] + gl4[3][tid][0];
    float G1 = gl4[0][tid][1] + gl4[1][tid][1] + gl4[2][tid][1] + gl4[3][tid][1];
    float G2 = gl4[0][tid][2] + gl4[1][tid][2] + gl4[2][tid][2] + gl4[3][tid][2];
    float G3 = gl4[0][tid][3] + gl4[1][tid][3] + gl4[2][tid][3] + gl4[3][tid][3];
    float c = c_state[(long)b * 512 + jgl];
    float iv = 1.f / (1.f + __expf(-G0));
    float fv = 1.f / (1.f + __expf(-G1));
    float e2 = __expf(2.f * G2); float gg = 1.f - 2.f / (e2 + 1.f);
    float ov = 1.f / (1.f + __expf(-G3));
    c = fv * c + iv * gg;
    float e3 = __expf(2.f * c); float tc = 1.f - 2.f / (e3 + 1.f);
    float hn = ov * tc;
    c_state[(long)b * 512 + jgl] = c;
    f16 hf = (f16)hn;
    hsl[tid] = hf;
    hout[(long)b * 512 + jgl] = hf;
    Hbuf[n * 512 + jgl] = hf;
  }
  __syncthreads();

  // ---- phase 5: att2 partial for NEXT step (UaT2 lanes-contiguous) ----
  {
    const unsigned* ua = (const unsigned*)UaT2 + (long)(q * 64) * 512 + tid;
    const f16x2* hv2 = (const f16x2*)hsl;
    float s0 = 0.f, s1 = 0.f;
#pragma unroll 8
    for (int j2 = 0; j2 < 64; j2 += 2) {
      s0 = fdot2f(hv2[j2], __builtin_bit_cast(f16x2, ua[(long)j2 * 512]), s0);
      s1 = fdot2f(hv2[j2 + 1], __builtin_bit_cast(f16x2, ua[(long)(j2 + 1) * 512]), s1);
    }
    a2pout[(long)b * 2048 + q * 512 + tid] = s0 + s1;
  }
}

extern "C" void kernel_launch(void* const* d_in, const int* in_sizes, int n_in,
                              void* d_out, int out_size, void* d_ws, size_t ws_size,
                              hipStream_t stream) {
  const int*   caps = (const int*)d_in[0];
  const float* feat = (const float*)d_in[1];
  const float* etab = (const float*)d_in[2];
  const float* W_a  = (const float*)d_in[3];
  const float* b_Wa = (const float*)d_in[4];
  const float* U_a  = (const float*)d_in[5];
  const float* b_Ua = (const float*)d_in[6];
  const float* v_a  = (const float*)d_in[7];
  /* d_in[8] b_va: softmax-invariant, unused */
  const float* W_ih = (const float*)d_in[9];
  const float* b_ih = (const float*)d_in[10];
  const float* W_hh = (const float*)d_in[11];
  const float* b_hh = (const float*)d_in[12];
  const float* fc_W = (const float*)d_in[13];
  const float* fc_b = (const float*)d_in[14];
  const float* Wh   = (const float*)d_in[15];
  const float* bh   = (const float*)d_in[16];
  const float* Wc   = (const float*)d_in[17];
  const float* bc   = (const float*)d_in[18];

  char* ws = (char*)d_ws;
  size_t off = 0;
  auto alloc = [&](size_t bytes) { void* p = ws + off; off += (bytes + 255) & ~(size_t)255; return p; };
  f16* feat_h  = (f16*)alloc(6553600ull * 2);   // [3200,2048] (3136 valid rows)
  f16* W_a_h   = (f16*)alloc(1048576ull * 2);   // H*F
  f16* W_ih_h  = (f16*)alloc(5242880ull * 2);   // 4H*(E+F)
  f16* fc_W_h  = (f16*)alloc(16384000ull * 2);  // V*H
  f16* Aemb    = (f16*)alloc(1048576ull * 2);   // B*S*E
  f16* WhhP    = (f16*)alloc(1048576ull * 2);   // W_hh gate-pack (uint4 @ [k2*512+j])
  f16* UaT2    = (f16*)alloc(262144ull * 2);    // U_a transpose-pack [j2][k] f16x2
  f16* Whc_h   = (f16*)alloc(2097152ull * 2);   // [Wh;Wc] = [1024,2048] f16
  f16* mean_h  = (f16*)alloc(131072ull * 2);    // [64,2048] mean features f16
  f16* att1_h  = (f16*)alloc(1638400ull * 2);   // [3200,512] (3136 valid)
  f16* featW4  = (f16*)alloc(6553600ull * 2);   // [3200,2048] g-interleaved (3136 valid)
  float* gates_x = (float*)alloc(4194304ull * 4); // B*S*4H
  float* Rh0   = (float*)alloc(65536ull * 4);   // [64,1024] h0/c0 GEMM out
  f16* hA      = (f16*)alloc(32768ull * 2);     // h ping
  f16* hB      = (f16*)alloc(32768ull * 2);     // h pong
  float* a2pA  = (float*)alloc(131072ull * 4);  // att2 partials ping [64][4][512]
  float* a2pB  = (float*)alloc(131072ull * 4);  // att2 partials pong
  float* c_state = (float*)alloc(32768ull * 4); // [64,512] c state
  f16* Hbuf    = (f16*)alloc(1048576ull * 2);   // B*S*H
  (void)ws_size; (void)in_sizes; (void)n_in; (void)out_size;

  float* out_logits = (float*)d_out;
  float* out_attw   = out_logits + 65536000ull;

  // Phase A: fused converts + packs + embedding gather, then precompute
  k_prep<<<4096, 256, 0, stream>>>(feat, W_a, W_ih, fc_W, W_hh, U_a, Wh, Wc, caps, etab,
                                   feat_h, W_a_h, W_ih_h, fc_W_h, WhhP, UaT2, Whc_h, Aemb);
  k_mean<<<dim3(64, 2), 256, 0, stream>>>(feat_h, mean_h);

  // h0/c0: [64,1024] = mean_h @ [Wh;Wc]^T  K=2048 -> f32 ; then split + initial att2 partials
  k_gemm<<<16, 256, 0, stream>>>(mean_h, 2048, Whc_h, 2048, Rh0, 1024, 2048, 1);
  k_h0a2p<<<dim3(64, 4), 512, 0, stream>>>(Rh0, bh, bc, UaT2, hA, c_state, a2pA);

  // att1 = features @ W_a^T + b_Wa         [3200,512]  K=2048 -> f16   (25 m x 4 n @128)
  k_gemm128b<<<25 * 4, 512, 0, stream>>>(feat_h, 2048, W_a_h, 2048,
                                         b_Wa, nullptr, att1_h, 512, 2048, 1, 25);
  // featW = features @ W_ih[:,E:]^T        [3200,2048] K=2048 -> f16 g-interleaved (25 x 8 @256)
  k_gemm256<<<25 * 8, 512, 0, stream>>>(feat_h, 2048, W_ih_h + 512, 2560,
                                        nullptr, nullptr, featW4, 0, 2048, 2, 25);
  // gates_x = embed @ W_ih[:,:E]^T + b_ih + b_hh   [2048,2048] K=512 -> f32 (16 x 8 @256)
  k_gemm256<<<16 * 8, 512, 0, stream>>>(Aemb, 512, W_ih_h, 2560,
                                        b_ih, b_hh, gates_x, 2048, 512, 0, 16);

  // Phase B: sequential recurrence — ONE dispatch per step (ping-pong h and att2p)
  for (int t = 0; t < 32; ++t) {
    const f16* hin = (t & 1) ? hB : hA;
    f16* hout = (t & 1) ? hA : hB;
    const float* a2i = (t & 1) ? a2pB : a2pA;
    float* a2o = (t & 1) ? a2pA : a2pB;
    k_fstep<<<dim3(64, 4), 512, 0, stream>>>(WhhP, UaT2, b_Ua, att1_h, v_a, featW4,
                                             gates_x, c_state, hin, hout, a2i, a2o,
                                             Hbuf, out_attw, t);
  }

  // Phase C: logits = H @ fc_W^T + fc_b    [2048,32000] K=512 -> f32 (16 m x 125 n @256)
  k_gemm256<<<16 * 125, 512, 0, stream>>>(Hbuf, 512, fc_W_h, 512,
                                          fc_b, nullptr, out_logits, 32000, 512, 0, 16);
}

// Round 16
// 829.697 us; speedup vs baseline: 1.0217x; 1.0213x over previous
//
#include <hip/hip_runtime.h>
#include <hip/hip_fp16.h>

typedef _Float16 f16;
typedef _Float16 f16x2 __attribute__((ext_vector_type(2)));
typedef _Float16 f16x4 __attribute__((ext_vector_type(4)));
typedef _Float16 f16x8 __attribute__((ext_vector_type(8)));
typedef float    f32x4 __attribute__((ext_vector_type(4)));

// Problem constants: B=64, S=32, P=49, F=2048, E=512, H=512, V=32000
// M=3136 (B*P) padded to 3200 for 128-row tiles.

#define GLD16(g, l)                                                        \
  __builtin_amdgcn_global_load_lds(                                        \
      (const __attribute__((address_space(1))) void*)(g),                  \
      (__attribute__((address_space(3))) void*)(l), 16, 0, 0)

static __device__ __forceinline__ float fdot2f(f16x2 a, f16x2 b, float c) {
#if __has_builtin(__builtin_amdgcn_fdot2)
  return __builtin_amdgcn_fdot2(a, b, c, false);
#else
  return c + (float)a.x * (float)b.x + (float)a.y * (float)b.y;
#endif
}

// ---------------- fused converts + packs + embedding gather (ONE dispatch) ----------------
// WhhP pack (R1-proven): uint4 at [k2*512 + j] = 4 gates x f16-pair (W_hh[g*512+j][2k2..2k2+1])
// UaT2 pack: f16x2 at dword [j2*512 + k] = (U_a[k][2j2], U_a[k][2j2+1])
__global__ __launch_bounds__(256) void k_prep(
    const float* __restrict__ feat, const float* __restrict__ W_a,
    const float* __restrict__ W_ih, const float* __restrict__ fc_W,
    const float* __restrict__ W_hh, const float* __restrict__ U_a,
    const float* __restrict__ Wh, const float* __restrict__ Wc,
    const int* __restrict__ caps, const float* __restrict__ etab,
    f16* __restrict__ feat_h, f16* __restrict__ W_a_h,
    f16* __restrict__ W_ih_h, f16* __restrict__ fc_W_h,
    f16* __restrict__ WhhP, f16* __restrict__ UaT2,
    f16* __restrict__ Whc_h, f16* __restrict__ Aemb) {
  const long c0 = 1605632;              // feat      (6422528 f32 /4)
  const long c1 = c0 + 262144;          // W_a
  const long c2 = c1 + 1310720;         // W_ih
  const long c3 = c2 + 4096000;         // fc_W
  const long c4 = c3 + 262144;          // W_hh -> WhhP pack
  const long c5 = c4 + 65536;           // U_a  -> UaT2 pack
  const long c6 = c5 + 262144;          // Wh   -> Whc rows 0..511
  const long c7 = c6 + 262144;          // Wc   -> Whc rows 512..1023
  const long c8 = c7 + 262144;          // embed: 2048 rows x 128 f16x4 chunks
  long i = (long)blockIdx.x * 256 + threadIdx.x;
  const long stride = (long)gridDim.x * 256;
  for (; i < c8; i += stride) {
    if (i >= c3 && i < c4) {            // W_hh pack region
      long ii = i - c3;                 // float4 index over W_hh [2048][512]
      int row = (int)(ii >> 7);         // = g*512 + j
      int c4i = (int)(ii & 127);
      int g = row >> 9, j = row & 511;
      float4 v = ((const float4*)W_hh)[ii];
      f16x2 p0; p0.x = (f16)v.x; p0.y = (f16)v.y;
      f16x2 p1; p1.x = (f16)v.z; p1.y = (f16)v.w;
      long k2a = 2 * (long)c4i;
      ((f16x2*)WhhP)[(k2a * 512 + j) * 4 + g] = p0;
      ((f16x2*)WhhP)[((k2a + 1) * 512 + j) * 4 + g] = p1;
      continue;
    }
    if (i >= c4 && i < c5) {            // U_a transpose-pack region
      long ii = i - c4;                 // float4 index over U_a [512][512]
      int k = (int)(ii >> 7);
      int j0 = (int)(ii & 127) * 4;
      float4 v = ((const float4*)U_a)[ii];
      f16x2 p0; p0.x = (f16)v.x; p0.y = (f16)v.y;
      f16x2 p1; p1.x = (f16)v.z; p1.y = (f16)v.w;
      ((f16x2*)UaT2)[(long)(j0 >> 1) * 512 + k] = p0;
      ((f16x2*)UaT2)[(long)((j0 >> 1) + 1) * 512 + k] = p1;
      continue;
    }
    const float4* s; f16x4* d; long j;
    if (i < c0)      { s = (const float4*)feat; d = (f16x4*)feat_h; j = i; }
    else if (i < c1) { s = (const float4*)W_a;  d = (f16x4*)W_a_h;  j = i - c0; }
    else if (i < c2) { s = (const float4*)W_ih; d = (f16x4*)W_ih_h; j = i - c1; }
    else if (i < c3) { s = (const float4*)fc_W; d = (f16x4*)fc_W_h; j = i - c2; }
    else if (i < c6) { s = (const float4*)Wh;   d = (f16x4*)Whc_h;  j = i - c5; }
    else if (i < c7) { s = (const float4*)Wc;   d = (f16x4*)(Whc_h + 1048576l); j = i - c6; }
    else {
      long jj = i - c7;                 // embedding gather region
      int n = (int)(jj >> 7), e4 = (int)(jj & 127);
      int tok = caps[n];
      s = (const float4*)(etab + (long)tok * 512); d = (f16x4*)(Aemb + (long)n * 512); j = e4;
    }
    float4 v = s[j];
    f16x4 o; o.x = (f16)v.x; o.y = (f16)v.y; o.z = (f16)v.z; o.w = (f16)v.w;
    d[j] = o;
  }
}

// ---------------- mean of features over P (from f16 feat) -> f16 [64,2048] ----------------
__global__ __launch_bounds__(256) void k_mean(const f16* __restrict__ feat_h,
                                              f16* __restrict__ mean_h) {
  int b = blockIdx.x;
  int e4 = blockIdx.y * 256 + threadIdx.x;
  const f16x4* src = (const f16x4*)(feat_h + (long)b * 49 * 2048) + e4;
  float s0 = 0.f, s1 = 0.f, s2 = 0.f, s3 = 0.f;
#pragma unroll 7
  for (int p = 0; p < 49; ++p) {
    f16x4 v = src[p * 512];
    s0 += (float)v.x; s1 += (float)v.y; s2 += (float)v.z; s3 += (float)v.w;
  }
  const float inv = 1.f / 49.f;
  f16x4 o; o.x = (f16)(s0 * inv); o.y = (f16)(s1 * inv); o.z = (f16)(s2 * inv); o.w = (f16)(s3 * inv);
  ((f16x4*)(mean_h + (long)b * 2048))[e4] = o;
}

// ---------------- h0/c0 split + biases + initial att2 partials (grid 64x4) ----------------
__global__ __launch_bounds__(512) void k_h0a2p(const float* __restrict__ Rh0,
                                               const float* __restrict__ bh,
                                               const float* __restrict__ bc,
                                               const f16* __restrict__ UaT2,
                                               f16* __restrict__ hA,
                                               float* __restrict__ c_state,
                                               float* __restrict__ a2pA) {
  __shared__ f16 hsl[128];
  const int b = blockIdx.x, q = blockIdx.y, tid = threadIdx.x;
  if (tid < 128) {
    int jg = q * 128 + tid;
    float hv = Rh0[(long)b * 1024 + jg] + bh[jg];
    c_state[(long)b * 512 + jg] = Rh0[(long)b * 1024 + 512 + jg] + bc[jg];
    f16 hf = (f16)hv;
    hsl[tid] = hf;
    hA[(long)b * 512 + jg] = hf;
  }
  __syncthreads();
  const unsigned* ua = (const unsigned*)UaT2 + (long)(q * 64) * 512 + tid;
  const f16x2* hv2 = (const f16x2*)hsl;
  float s0 = 0.f, s1 = 0.f;
#pragma unroll 8
  for (int j2 = 0; j2 < 64; j2 += 2) {
    s0 = fdot2f(hv2[j2], __builtin_bit_cast(f16x2, ua[(long)j2 * 512]), s0);
    s1 = fdot2f(hv2[j2 + 1], __builtin_bit_cast(f16x2, ua[(long)(j2 + 1) * 512]), s1);
  }
  a2pA[(long)b * 2048 + q * 512 + tid] = s0 + s1;
}

// ---------------- generic f16 MFMA GEMM (64x64 tile) — used only for h0/c0 (M=64) ----------
__global__ __launch_bounds__(256) void k_gemm(const f16* __restrict__ A, long lda,
                                              const f16* __restrict__ Bw, long ldb,
                                              float* __restrict__ Cout, long ldc,
                                              int K, int n_mtiles) {
  __shared__ f16 As[64][40];
  __shared__ f16 Bs[64][40];
  const int tid = threadIdx.x;
  const int lane = tid & 63, wave = tid >> 6;
  const int bid = blockIdx.x;
  const long m0 = (long)(bid % n_mtiles) * 64, n0 = (long)(bid / n_mtiles) * 64;
  const int lr = tid >> 2, lc = (tid & 3) * 8;
  const int wr = (wave >> 1) * 32, wc = (wave & 1) * 32;
  f32x4 acc[2][2] = {};
  const f16* Ap = A + (m0 + lr) * lda + lc;
  const f16* Bp = Bw + (n0 + lr) * ldb + lc;
  for (int k0 = 0; k0 < K; k0 += 32) {
    uint4 av = *(const uint4*)(Ap + k0);
    uint4 bv = *(const uint4*)(Bp + k0);
    __syncthreads();
    *(uint4*)&As[lr][lc] = av;
    *(uint4*)&Bs[lr][lc] = bv;
    __syncthreads();
#pragma unroll
    for (int mi = 0; mi < 2; ++mi) {
      f16x8 af = *(const f16x8*)&As[wr + mi * 16 + (lane & 15)][(lane >> 4) * 8];
#pragma unroll
      for (int ni = 0; ni < 2; ++ni) {
        f16x8 bf = *(const f16x8*)&Bs[wc + ni * 16 + (lane & 15)][(lane >> 4) * 8];
        acc[mi][ni] = __builtin_amdgcn_mfma_f32_16x16x32_f16(af, bf, acc[mi][ni], 0, 0, 0);
      }
    }
  }
#pragma unroll
  for (int mi = 0; mi < 2; ++mi)
#pragma unroll
    for (int ni = 0; ni < 2; ++ni) {
      int row_b = wr + mi * 16 + (lane >> 4) * 4;
      long gcol = n0 + wc + ni * 16 + (lane & 15);
#pragma unroll
      for (int r = 0; r < 4; ++r)
        Cout[(m0 + row_b + r) * ldc + gcol] = acc[mi][ni][r];
    }
}

// ---------------- 128x128 tile, BK=64, global_load_lds staging, XOR-swizzled LDS ------------
__global__ __launch_bounds__(512) void k_gemm128b(const f16* __restrict__ A, long lda,
                                                  const f16* __restrict__ Bw, long ldb,
                                                  const float* __restrict__ bias1,
                                                  const float* __restrict__ bias2,
                                                  void* __restrict__ Cout, long ldc,
                                                  int K, int mode, int n_mtiles) {
  __shared__ f16 As[8192];   // [128][64] = 16 KB
  __shared__ f16 Bs[8192];
  const int tid = threadIdx.x, lane = tid & 63, wave = tid >> 6;
  const int wm = wave & 3, wn = wave >> 2;
  const int bid = blockIdx.x;
  const long m0 = (long)(bid % n_mtiles) * 128, n0 = (long)(bid / n_mtiles) * 128;
  const int c0 = wave * 128 + lane, c1 = c0 + 64;
  const int r0 = c0 >> 3, s0 = (c0 & 7) ^ (r0 & 7);
  const int r1 = c1 >> 3, s1 = (c1 & 7) ^ (r1 & 7);
  const f16* gA0 = A + (m0 + r0) * lda + s0 * 8;
  const f16* gA1 = A + (m0 + r1) * lda + s1 * 8;
  const f16* gB0 = Bw + (n0 + r0) * ldb + s0 * 8;
  const f16* gB1 = Bw + (n0 + r1) * ldb + s1 * 8;
  f16* lA0 = As + (wave * 128) * 8;
  f16* lA1 = As + (wave * 128 + 64) * 8;
  f16* lB0 = Bs + (wave * 128) * 8;
  f16* lB1 = Bs + (wave * 128 + 64) * 8;
  f32x4 acc[2][4] = {};
  for (int k0 = 0; k0 < K; k0 += 64) {
    GLD16(gA0 + k0, lA0); GLD16(gA1 + k0, lA1);
    GLD16(gB0 + k0, lB0); GLD16(gB1 + k0, lB1);
    __syncthreads();
#pragma unroll
    for (int ks = 0; ks < 2; ++ks) {
      const int sp = (ks * 4 + (lane >> 4)) ^ (lane & 7);
#pragma unroll
      for (int mi = 0; mi < 2; ++mi) {
        const int rA = wm * 32 + mi * 16 + (lane & 15);
        f16x8 af = *(const f16x8*)(As + rA * 64 + sp * 8);
#pragma unroll
        for (int ni = 0; ni < 4; ++ni) {
          const int rB = wn * 64 + ni * 16 + (lane & 15);
          f16x8 bf = *(const f16x8*)(Bs + rB * 64 + sp * 8);
          acc[mi][ni] = __builtin_amdgcn_mfma_f32_16x16x32_f16(af, bf, acc[mi][ni], 0, 0, 0);
        }
      }
    }
    __syncthreads();
  }
#pragma unroll
  for (int mi = 0; mi < 2; ++mi)
#pragma unroll
    for (int ni = 0; ni < 4; ++ni) {
      int row_b = wm * 32 + mi * 16 + (lane >> 4) * 4;
      long gcol = n0 + wn * 64 + ni * 16 + (lane & 15);
      float badd = (bias1 ? bias1[gcol] : 0.f) + (bias2 ? bias2[gcol] : 0.f);
#pragma unroll
      for (int r = 0; r < 4; ++r) {
        long grow = m0 + row_b + r;
        float v = acc[mi][ni][r] + badd;
        if (mode == 0)      ((float*)Cout)[grow * ldc + gcol] = v;
        else if (mode == 1) ((f16*)Cout)[grow * ldc + gcol] = (f16)v;
        else                ((f16*)Cout)[grow * 2048 + ((gcol & 511) << 2) + (gcol >> 9)] = (f16)v;
      }
    }
}

// ---------------- fused full step, ONE dispatch per t, grid (64 b, 4 q) --------------------
// R12 version (phase-overlap): W_hh L2 stream ∥ scores VALU in one barrier-free region;
// featW ctx operands prefetched to registers; gates_x folded into w=0 partial.
__global__ __launch_bounds__(512) void k_fstep(
    const f16* __restrict__ WhhP, const f16* __restrict__ UaT2,
    const float* __restrict__ b_Ua, const f16* __restrict__ att1,
    const float* __restrict__ va, const f16* __restrict__ featW4,
    const float* __restrict__ gates_x, float* __restrict__ c_state,
    const f16* __restrict__ hin, f16* __restrict__ hout,
    const float* __restrict__ a2pin, float* __restrict__ a2pout,
    f16* __restrict__ Hbuf, float* __restrict__ attw_out, int t) {
  __shared__ __align__(16) f16 hh[512];
  __shared__ float att2[512];
  __shared__ float sc[64];
  __shared__ float wl[49];
  __shared__ __align__(16) float gl4[4][128][4];   // per-w gate partials
  __shared__ __align__(16) f16 hsl[128];
  const int b = blockIdx.x, q = blockIdx.y, tid = threadIdx.x;
  const int lane = tid & 63, wave = tid >> 6;
  const long n = (long)b * 32 + t;
  const int jj = tid & 127, w = tid >> 7, jg = q * 128 + jj;

  // ---- phase 0: h + att2 assembly (1 barrier) ----
  hh[tid] = hin[(long)b * 512 + tid];
  const float* ap = a2pin + (long)b * 2048;
  att2[tid] = b_Ua[tid] + ap[tid] + ap[512 + tid] + ap[1024 + tid] + ap[1536 + tid];
  __syncthreads();

  // ---- phase 1 (barrier-free): W_hh gate partials ∥ featW prefetch ∥ scores ----
  float g0, g1, g2, g3;
  if (w == 0) {               // fold gates_x into the w=0 partial
    const float* gx = gates_x + n * 2048;
    g0 = gx[jg]; g1 = gx[512 + jg]; g2 = gx[1024 + jg]; g3 = gx[1536 + jg];
  } else {
    g0 = g1 = g2 = g3 = 0.f;
  }
  uint2 fwv[13];
  {
    const f16* fw = featW4 + (long)(b * 49) * 2048 + q * 512 + jj * 4;
#pragma unroll
    for (int i = 0; i < 13; ++i) {
      int p = w + 4 * i; if (p > 48) p = 48;
      fwv[i] = *(const uint2*)(fw + (long)p * 2048);
    }
  }
  {
    const uint4* W4 = (const uint4*)WhhP;
    const f16x2* hp = (const f16x2*)hh;
#pragma unroll 8
    for (int k2 = w * 64; k2 < w * 64 + 64; ++k2) {
      uint4 wv4 = W4[(long)k2 * 512 + jg];
      f16x2 hv = hp[k2];
      g0 = fdot2f(hv, __builtin_bit_cast(f16x2, wv4.x), g0);
      g1 = fdot2f(hv, __builtin_bit_cast(f16x2, wv4.y), g1);
      g2 = fdot2f(hv, __builtin_bit_cast(f16x2, wv4.z), g2);
      g3 = fdot2f(hv, __builtin_bit_cast(f16x2, wv4.w), g3);
    }
  }
  // scores: wave w' handles p = w', w'+8, ... (overlaps other waves' W_hh memory)
  for (int p = wave; p < 49; p += 8) {
    const f16* arow = att1 + ((long)b * 49 + p) * 512;
    float s = 0.f;
#pragma unroll
    for (int kk = 0; kk < 8; ++kk) {
      int k = lane + kk * 64;
      float x = (float)arow[k] + att2[k];
      float e = __expf(2.f * x);
      s += va[k] * (1.f - 2.f / (e + 1.f));
    }
#pragma unroll
    for (int off = 32; off; off >>= 1) s += __shfl_xor(s, off);
    if (lane == 0) sc[p] = s;
  }
  __syncthreads();

  // ---- phase 2: softmax over P=49 (wave 0; b_va softmax-invariant) ----
  if (wave == 0) {
    float s = (lane < 49) ? sc[lane] : -1e30f;
    float m = s;
#pragma unroll
    for (int off = 32; off; off >>= 1) m = fmaxf(m, __shfl_xor(m, off));
    float e = (lane < 49) ? __expf(s - m) : 0.f;
    float sum = e;
#pragma unroll
    for (int off = 32; off; off >>= 1) sum += __shfl_xor(sum, off);
    float wv = e / sum;
    if (lane < 49) {
      wl[lane] = wv;
      if (q == 0) attw_out[n * 49 + lane] = wv;
    }
  }
  __syncthreads();

  // ---- phase 3: ctx accumulation from prefetched registers ----
#pragma unroll
  for (int i = 0; i < 13; ++i) {
    int p = w + 4 * i;
    if (p < 49) {
      float wp = wl[p];
      f16x2 aa = __builtin_bit_cast(f16x2, fwv[i].x);
      f16x2 bb = __builtin_bit_cast(f16x2, fwv[i].y);
      g0 += wp * (float)aa.x; g1 += wp * (float)aa.y;
      g2 += wp * (float)bb.x; g3 += wp * (float)bb.y;
    }
  }
  {
    float4 gv4; gv4.x = g0; gv4.y = g1; gv4.z = g2; gv4.w = g3;
    *(float4*)&gl4[w][jj][0] = gv4;
  }
  __syncthreads();

  // ---- phase 4: LSTM pointwise (tid < 128) ----
  if (tid < 128) {
    int jgl = q * 128 + tid;
    float G0 = gl4[0][tid][0] + gl4[1][tid][0] + gl4[2][tid][0] + gl4[3][tid][0];
    float G1 = gl4[0][tid][1] + gl4[1][tid][1] + gl4[2][tid][1] + gl4[3][tid][1];
    float G2 = gl4[0][tid][2] + gl4[1][tid][2] + gl4[2][tid][2] + gl4[3][tid][2];
    float G3 = gl4[0][tid][3] + gl4[1][tid][3] + gl4[2][tid][3] + gl4[3][tid][3];
    float c = c_state[(long)b * 512 + jgl];
    float iv = 1.f / (1.f + __expf(-G0));
    float fv = 1.f / (1.f + __expf(-G1));
    float e2 = __expf(2.f * G2); float gg = 1.f - 2.f / (e2 + 1.f);
    float ov = 1.f / (1.f + __expf(-G3));
    c = fv * c + iv * gg;
    float e3 = __expf(2.f * c); float tc = 1.f - 2.f / (e3 + 1.f);
    float hn = ov * tc;
    c_state[(long)b * 512 + jgl] = c;
    f16 hf = (f16)hn;
    hsl[tid] = hf;
    hout[(long)b * 512 + jgl] = hf;
    Hbuf[n * 512 + jgl] = hf;
  }
  __syncthreads();

  // ---- phase 5: att2 partial for NEXT step (UaT2 lanes-contiguous) ----
  {
    const unsigned* ua = (const unsigned*)UaT2 + (long)(q * 64) * 512 + tid;
    const f16x2* hv2 = (const f16x2*)hsl;
    float s0 = 0.f, s1 = 0.f;
#pragma unroll 8
    for (int j2 = 0; j2 < 64; j2 += 2) {
      s0 = fdot2f(hv2[j2], __builtin_bit_cast(f16x2, ua[(long)j2 * 512]), s0);
      s1 = fdot2f(hv2[j2 + 1], __builtin_bit_cast(f16x2, ua[(long)(j2 + 1) * 512]), s1);
    }
    a2pout[(long)b * 2048 + q * 512 + tid] = s0 + s1;
  }
}

extern "C" void kernel_launch(void* const* d_in, const int* in_sizes, int n_in,
                              void* d_out, int out_size, void* d_ws, size_t ws_size,
                              hipStream_t stream) {
  const int*   caps = (const int*)d_in[0];
  const float* feat = (const float*)d_in[1];
  const float* etab = (const float*)d_in[2];
  const float* W_a  = (const float*)d_in[3];
  const float* b_Wa = (const float*)d_in[4];
  const float* U_a  = (const float*)d_in[5];
  const float* b_Ua = (const float*)d_in[6];
  const float* v_a  = (const float*)d_in[7];
  /* d_in[8] b_va: softmax-invariant, unused */
  const float* W_ih = (const float*)d_in[9];
  const float* b_ih = (const float*)d_in[10];
  const float* W_hh = (const float*)d_in[11];
  const float* b_hh = (const float*)d_in[12];
  const float* fc_W = (const float*)d_in[13];
  const float* fc_b = (const float*)d_in[14];
  const float* Wh   = (const float*)d_in[15];
  const float* bh   = (const float*)d_in[16];
  const float* Wc   = (const float*)d_in[17];
  const float* bc   = (const float*)d_in[18];

  char* ws = (char*)d_ws;
  size_t off = 0;
  auto alloc = [&](size_t bytes) { void* p = ws + off; off += (bytes + 255) & ~(size_t)255; return p; };
  f16* feat_h  = (f16*)alloc(6553600ull * 2);   // [3200,2048] (3136 valid rows)
  f16* W_a_h   = (f16*)alloc(1048576ull * 2);   // H*F
  f16* W_ih_h  = (f16*)alloc(5242880ull * 2);   // 4H*(E+F)
  f16* fc_W_h  = (f16*)alloc(16384000ull * 2);  // V*H
  f16* Aemb    = (f16*)alloc(1048576ull * 2);   // B*S*E
  f16* WhhP    = (f16*)alloc(1048576ull * 2);   // W_hh gate-pack (uint4 @ [k2*512+j])
  f16* UaT2    = (f16*)alloc(262144ull * 2);    // U_a transpose-pack [j2][k] f16x2
  f16* Whc_h   = (f16*)alloc(2097152ull * 2);   // [Wh;Wc] = [1024,2048] f16
  f16* mean_h  = (f16*)alloc(131072ull * 2);    // [64,2048] mean features f16
  f16* att1_h  = (f16*)alloc(1638400ull * 2);   // [3200,512] (3136 valid)
  f16* featW4  = (f16*)alloc(6553600ull * 2);   // [3200,2048] g-interleaved (3136 valid)
  float* gates_x = (float*)alloc(4194304ull * 4); // B*S*4H
  float* Rh0   = (float*)alloc(65536ull * 4);   // [64,1024] h0/c0 GEMM out
  f16* hA      = (f16*)alloc(32768ull * 2);     // h ping
  f16* hB      = (f16*)alloc(32768ull * 2);     // h pong
  float* a2pA  = (float*)alloc(131072ull * 4);  // att2 partials ping [64][4][512]
  float* a2pB  = (float*)alloc(131072ull * 4);  // att2 partials pong
  float* c_state = (float*)alloc(32768ull * 4); // [64,512] c state
  f16* Hbuf    = (f16*)alloc(1048576ull * 2);   // B*S*H
  (void)ws_size; (void)in_sizes; (void)n_in; (void)out_size;

  float* out_logits = (float*)d_out;
  float* out_attw   = out_logits + 65536000ull;

  // Phase A: fused converts + packs + embedding gather, then precompute
  k_prep<<<4096, 256, 0, stream>>>(feat, W_a, W_ih, fc_W, W_hh, U_a, Wh, Wc, caps, etab,
                                   feat_h, W_a_h, W_ih_h, fc_W_h, WhhP, UaT2, Whc_h, Aemb);
  k_mean<<<dim3(64, 2), 256, 0, stream>>>(feat_h, mean_h);

  // h0/c0: [64,1024] = mean_h @ [Wh;Wc]^T  K=2048 -> f32 ; then split + initial att2 partials
  k_gemm<<<16, 256, 0, stream>>>(mean_h, 2048, Whc_h, 2048, Rh0, 1024, 2048, 1);
  k_h0a2p<<<dim3(64, 4), 512, 0, stream>>>(Rh0, bh, bc, UaT2, hA, c_state, a2pA);

  // att1 = features @ W_a^T + b_Wa         [3200,512]  K=2048 -> f16   (25 m x 4 n)
  k_gemm128b<<<25 * 4, 512, 0, stream>>>(feat_h, 2048, W_a_h, 2048,
                                         b_Wa, nullptr, att1_h, 512, 2048, 1, 25);
  // featW = features @ W_ih[:,E:]^T        [3200,2048] K=2048 -> f16 g-interleaved (25 x 16)
  k_gemm128b<<<25 * 16, 512, 0, stream>>>(feat_h, 2048, W_ih_h + 512, 2560,
                                          nullptr, nullptr, featW4, 0, 2048, 2, 25);
  // gates_x = embed @ W_ih[:,:E]^T + b_ih + b_hh   [2048,2048] K=512 -> f32 (16 x 16)
  k_gemm128b<<<16 * 16, 512, 0, stream>>>(Aemb, 512, W_ih_h, 2560,
                                          b_ih, b_hh, gates_x, 2048, 512, 0, 16);

  // Phase B: sequential recurrence — ONE dispatch per step (ping-pong h and att2p)
  for (int t = 0; t < 32; ++t) {
    const f16* hin = (t & 1) ? hB : hA;
    f16* hout = (t & 1) ? hA : hB;
    const float* a2i = (t & 1) ? a2pB : a2pA;
    float* a2o = (t & 1) ? a2pA : a2pB;
    k_fstep<<<dim3(64, 4), 512, 0, stream>>>(WhhP, UaT2, b_Ua, att1_h, v_a, featW4,
                                             gates_x, c_state, hin, hout, a2i, a2o,
                                             Hbuf, out_attw, t);
  }

  // Phase C: logits = H @ fc_W^T + fc_b    [2048,32000] K=512 -> f32 (16 m x 250 n)
  k_gemm128b<<<16 * 250, 512, 0, stream>>>(Hbuf, 512, fc_W_h, 512,
                                           fc_b, nullptr, out_logits, 32000, 512, 0, 16);
}